// Round 1
// baseline (1088.409 us; speedup 1.0000x reference)
//
#include <hip/hip_runtime.h>
#include <math.h>

namespace {

constexpr int NN = 50000;
constexpr int EE = 400000;
constexpr int CIN = 512;
constexpr int GH = 128;
constexpr int GO = 64;
constexpr int THD = 64;    // head dim
constexpr int HEADS = 4;
constexpr int COUT = 32;
constexpr float EPS = 1e-5f;

__device__ __forceinline__ int fmap(float f) {
  int b = __float_as_int(f);
  return b >= 0 ? b : (b ^ 0x7FFFFFFF);
}
__device__ __forceinline__ float funmap(int k) {
  int b = k >= 0 ? k : (k ^ 0x7FFFFFFF);
  return __int_as_float(b);
}

// ---- graph norm prep ----------------------------------------------------
__global__ void k_init(float* deg, int* smax, float* denom) {
  int i = blockIdx.x * blockDim.x + threadIdx.x;
  if (i < NN) deg[i] = 0.0f;
  if (i < NN * HEADS) { smax[i] = (int)0x807FFFFF; denom[i] = 0.0f; }
}

__global__ void k_deg(const int* __restrict__ ei, const float* __restrict__ w,
                      float* __restrict__ deg) {
  int e = blockIdx.x * blockDim.x + threadIdx.x;
  if (e < EE) atomicAdd(&deg[ei[EE + e]], w[e]);
}

__global__ void k_dinv(float* deg) {
  int i = blockIdx.x * blockDim.x + threadIdx.x;
  if (i < NN) deg[i] = rsqrtf(deg[i] + 1.0f);  // self-loop weight 1 included
}

__global__ void k_norm(const int* __restrict__ ei, const float* __restrict__ w,
                       const float* __restrict__ dinv, float* __restrict__ norm) {
  int e = blockIdx.x * blockDim.x + threadIdx.x;
  if (e < EE) norm[e] = dinv[ei[e]] * w[e] * dinv[ei[EE + e]];
}

// ---- generic fp32 SGEMM: C[M,F] = A[M,K] @ B[K,F] (+bias) ---------------
// 256 threads; thread computes TM x TN outputs; block rows BM = (256/(F/TN))*TM
template <int F, int TM, int TN>
__launch_bounds__(256) __global__
void sgemm(const float* __restrict__ A, const float* __restrict__ B,
           const float* __restrict__ bias, float* __restrict__ C,
           int M, int K) {
  constexpr int KT = 32;
  constexpr int TC = F / TN;       // threads across cols
  constexpr int TR = 256 / TC;     // thread rows
  constexpr int BM = TR * TM;      // block rows
  constexpr int NJ = TN / 4;       // float4 chunks per thread

  __shared__ float As[BM][KT + 4];
  __shared__ float Bs[KT][F];

  const int tid = threadIdx.x;
  const int tc = tid % TC;
  const int tr = tid / TC;
  const int m0 = blockIdx.x * BM;

  float acc[TM][TN];
#pragma unroll
  for (int i = 0; i < TM; ++i)
#pragma unroll
    for (int j = 0; j < TN; ++j) acc[i][j] = 0.0f;

  constexpr int totA4 = BM * KT / 4;
  constexpr int totB4 = KT * F / 4;

  for (int k0 = 0; k0 < K; k0 += KT) {
    // stage A tile (BM x KT), float4 on K
#pragma unroll
    for (int idx = tid; idx < totA4; idx += 256) {
      int flat = idx * 4;
      int r = flat / KT, c = flat % KT;
      float4 val = make_float4(0.f, 0.f, 0.f, 0.f);
      int gr = m0 + r;
      if (gr < M) val = *reinterpret_cast<const float4*>(A + (size_t)gr * K + k0 + c);
      *reinterpret_cast<float4*>(&As[r][c]) = val;
    }
    // stage B tile (KT x F), contiguous copy
    {
      const float4* Bg = reinterpret_cast<const float4*>(B + (size_t)k0 * F);
      float4* Bs4 = reinterpret_cast<float4*>(&Bs[0][0]);
#pragma unroll
      for (int idx = tid; idx < totB4; idx += 256) Bs4[idx] = Bg[idx];
    }
    __syncthreads();

#pragma unroll
    for (int kk = 0; kk < KT; ++kk) {
      float a[TM];
#pragma unroll
      for (int i = 0; i < TM; ++i) a[i] = As[tr * TM + i][kk];
      float4 b[NJ];
      const float4* Brow = reinterpret_cast<const float4*>(&Bs[kk][0]);
#pragma unroll
      for (int j = 0; j < NJ; ++j) b[j] = Brow[tc + j * TC];
#pragma unroll
      for (int i = 0; i < TM; ++i) {
#pragma unroll
        for (int j = 0; j < NJ; ++j) {
          acc[i][j * 4 + 0] += a[i] * b[j].x;
          acc[i][j * 4 + 1] += a[i] * b[j].y;
          acc[i][j * 4 + 2] += a[i] * b[j].z;
          acc[i][j * 4 + 3] += a[i] * b[j].w;
        }
      }
    }
    __syncthreads();
  }

  float4 bias4[NJ];
#pragma unroll
  for (int j = 0; j < NJ; ++j) {
    bias4[j] = bias ? reinterpret_cast<const float4*>(bias)[tc + j * TC]
                    : make_float4(0.f, 0.f, 0.f, 0.f);
  }
#pragma unroll
  for (int i = 0; i < TM; ++i) {
    int gr = m0 + tr * TM + i;
    if (gr >= M) continue;
    float4* Crow = reinterpret_cast<float4*>(C + (size_t)gr * F);
#pragma unroll
    for (int j = 0; j < NJ; ++j) {
      float4 v;
      v.x = acc[i][j * 4 + 0] + bias4[j].x;
      v.y = acc[i][j * 4 + 1] + bias4[j].y;
      v.z = acc[i][j * 4 + 2] + bias4[j].z;
      v.w = acc[i][j * 4 + 3] + bias4[j].w;
      Crow[tc + j * TC] = v;
    }
  }
}

// ---- GCN propagation ----------------------------------------------------
template <int F>
__global__ void k_selfinit(const float* __restrict__ h, const float* __restrict__ dinv,
                           float* __restrict__ out) {
  int i = blockIdx.x * blockDim.x + threadIdx.x;
  if (i < NN * F) {
    int n = i / F;
    float di = dinv[n];
    out[i] = di * di * h[i];
  }
}

template <int F>
__global__ void k_scatter(const int* __restrict__ ei, const float* __restrict__ norm,
                          const float* __restrict__ h, float* __restrict__ out) {
  int i = blockIdx.x * blockDim.x + threadIdx.x;
  if (i >= EE * F) return;
  int e = i / F;
  int f = i - e * F;
  int s = ei[e], d = ei[EE + e];
  atomicAdd(&out[d * F + f], norm[e] * h[s * F + f]);
}

template <int F>
__global__ void k_bnrelu(float* __restrict__ h, const float* __restrict__ bias,
                         const float* __restrict__ g, const float* __restrict__ be,
                         const float* __restrict__ m, const float* __restrict__ v) {
  int i = blockIdx.x * blockDim.x + threadIdx.x;
  if (i < NN * F) {
    int f = i % F;
    float s = g[f] * rsqrtf(v[f] + EPS);
    float b = bias ? bias[f] : 0.0f;
    float y = (h[i] + b - m[f]) * s + be[f];
    h[i] = y > 0.0f ? y : 0.0f;
  }
}

// ---- transformer conv ---------------------------------------------------
__global__ void k_score(const int* __restrict__ ei, const float* __restrict__ q,
                        const float* __restrict__ kk, float* __restrict__ sc,
                        int* __restrict__ smax) {
  int t = blockIdx.x * blockDim.x + threadIdx.x;
  if (t >= EE * HEADS) return;
  int e = t >> 2, h = t & 3;
  int s = ei[e], d = ei[EE + e];
  const float4* qr = reinterpret_cast<const float4*>(q + (size_t)d * 256 + h * 64);
  const float4* kr = reinterpret_cast<const float4*>(kk + (size_t)s * 256 + h * 64);
  float acc = 0.f;
#pragma unroll
  for (int i = 0; i < 16; ++i) {
    float4 a = qr[i], b = kr[i];
    acc += a.x * b.x + a.y * b.y + a.z * b.z + a.w * b.w;
  }
  acc *= 0.125f;  // / sqrt(64)
  sc[t] = acc;
  atomicMax(&smax[d * 4 + h], fmap(acc));
}

__global__ void k_expsum(const int* __restrict__ ei, float* __restrict__ sc,
                         const int* __restrict__ smax, float* __restrict__ denom) {
  int t = blockIdx.x * blockDim.x + threadIdx.x;
  if (t >= EE * HEADS) return;
  int e = t >> 2, h = t & 3;
  int d = ei[EE + e];
  float mx = funmap(smax[d * 4 + h]);
  float ex = expf(sc[t] - mx);
  sc[t] = ex;
  atomicAdd(&denom[d * 4 + h], ex);
}

__global__ void k_alpha(const int* __restrict__ ei, float* __restrict__ sc,
                        const float* __restrict__ denom) {
  int t = blockIdx.x * blockDim.x + threadIdx.x;
  if (t >= EE * HEADS) return;
  int e = t >> 2, h = t & 3;
  int d = ei[EE + e];
  sc[t] = sc[t] / (denom[d * 4 + h] + 1e-16f) * 0.25f;  // fold 1/HEADS mean
}

__global__ void k_agg(const int* __restrict__ ei, const float* __restrict__ alpha,
                      const float* __restrict__ v, float* __restrict__ agg) {
  int i = blockIdx.x * blockDim.x + threadIdx.x;
  if (i >= EE * THD) return;
  int e = i >> 6;
  int dd = i & 63;
  int s = ei[e], d = ei[EE + e];
  const float* al = alpha + (size_t)e * 4;
  const float* vr = v + (size_t)s * 256;
  float sum = al[0] * vr[dd] + al[1] * vr[64 + dd] + al[2] * vr[128 + dd] +
              al[3] * vr[192 + dd];
  atomicAdd(&agg[d * THD + dd], sum);
}

inline int cdiv(int a, int b) { return (a + b - 1) / b; }

}  // namespace

extern "C" void kernel_launch(void* const* d_in, const int* in_sizes, int n_in,
                              void* d_out, int out_size, void* d_ws, size_t ws_size,
                              hipStream_t stream) {
  const float* x   = (const float*)d_in[0];
  const int*   ei  = (const int*)d_in[1];
  const float* ew  = (const float*)d_in[2];
  const float* W1  = (const float*)d_in[3];
  const float* b1  = (const float*)d_in[4];
  const float* g1  = (const float*)d_in[5];
  const float* be1 = (const float*)d_in[6];
  const float* m1  = (const float*)d_in[7];
  const float* v1  = (const float*)d_in[8];
  const float* W2  = (const float*)d_in[9];
  const float* b2  = (const float*)d_in[10];
  const float* g2  = (const float*)d_in[11];
  const float* be2 = (const float*)d_in[12];
  const float* m2  = (const float*)d_in[13];
  const float* v2  = (const float*)d_in[14];
  const float* Wq  = (const float*)d_in[15];
  const float* bq  = (const float*)d_in[16];
  const float* Wk  = (const float*)d_in[17];
  const float* bk  = (const float*)d_in[18];
  const float* Wv  = (const float*)d_in[19];
  const float* bv  = (const float*)d_in[20];
  const float* Wsk = (const float*)d_in[21];
  const float* bsk = (const float*)d_in[22];
  const float* gt  = (const float*)d_in[23];
  const float* bet = (const float*)d_in[24];
  const float* mt  = (const float*)d_in[25];
  const float* vt  = (const float*)d_in[26];
  const float* Wfc = (const float*)d_in[27];
  const float* bfc = (const float*)d_in[28];

  float* ws = (float*)d_ws;
  float* dinv  = ws;                       // N
  float* norm  = dinv + NN;                // E
  float* h1    = norm + EE;                // N*128  (h2 reuses first N*64)
  float* hp1   = h1 + (size_t)NN * GH;     // N*128  (z reuses)
  float* q     = hp1 + (size_t)NN * GH;    // N*256
  float* kbuf  = q + (size_t)NN * 256;     // N*256
  float* vbuf  = kbuf + (size_t)NN * 256;  // N*256
  float* agg   = vbuf + (size_t)NN * 256;  // N*64
  int*   smax  = (int*)(agg + (size_t)NN * GO);   // N*4
  float* denom = (float*)(smax + NN * HEADS);     // N*4
  float* sc    = denom + NN * HEADS;              // E*4

  float* h2 = h1;   // reuse after h1 consumed
  float* z  = hp1;  // reuse after hp1 consumed

  const int tb = 256;

  k_init<<<cdiv(NN * HEADS, tb), tb, 0, stream>>>(dinv, smax, denom);
  k_deg<<<cdiv(EE, tb), tb, 0, stream>>>(ei, ew, dinv);
  k_dinv<<<cdiv(NN, tb), tb, 0, stream>>>(dinv);
  k_norm<<<cdiv(EE, tb), tb, 0, stream>>>(ei, ew, dinv, norm);

  // ---- GCN layer 1: h1 = x @ W1 ; propagate ; BN1+ReLU
  sgemm<GH, 8, 8><<<cdiv(NN, 128), 256, 0, stream>>>(x, W1, nullptr, h1, NN, CIN);
  k_selfinit<GH><<<cdiv(NN * GH, tb), tb, 0, stream>>>(h1, dinv, hp1);
  k_scatter<GH><<<cdiv(EE * GH, tb), tb, 0, stream>>>(ei, norm, h1, hp1);
  k_bnrelu<GH><<<cdiv(NN * GH, tb), tb, 0, stream>>>(hp1, b1, g1, be1, m1, v1);

  // ---- GCN layer 2: h2 = hp1 @ W2 ; propagate ; BN2+ReLU
  sgemm<GO, 4, 8><<<cdiv(NN, 128), 256, 0, stream>>>(hp1, W2, nullptr, h2, NN, GH);
  k_selfinit<GO><<<cdiv(NN * GO, tb), tb, 0, stream>>>(h2, dinv, z);
  k_scatter<GO><<<cdiv(EE * GO, tb), tb, 0, stream>>>(ei, norm, h2, z);
  k_bnrelu<GO><<<cdiv(NN * GO, tb), tb, 0, stream>>>(z, b2, g2, be2, m2, v2);

  // ---- TransformerConv
  sgemm<256, 8, 8><<<cdiv(NN, 64), 256, 0, stream>>>(z, Wq, bq, q, NN, GO);
  sgemm<256, 8, 8><<<cdiv(NN, 64), 256, 0, stream>>>(z, Wk, bk, kbuf, NN, GO);
  sgemm<256, 8, 8><<<cdiv(NN, 64), 256, 0, stream>>>(z, Wv, bv, vbuf, NN, GO);
  // agg initialized with skip connection: z @ Wskip + bskip
  sgemm<GO, 4, 8><<<cdiv(NN, 128), 256, 0, stream>>>(z, Wsk, bsk, agg, NN, GO);

  k_score<<<cdiv(EE * HEADS, tb), tb, 0, stream>>>(ei, q, kbuf, sc, smax);
  k_expsum<<<cdiv(EE * HEADS, tb), tb, 0, stream>>>(ei, sc, smax, denom);
  k_alpha<<<cdiv(EE * HEADS, tb), tb, 0, stream>>>(ei, sc, denom);
  k_agg<<<cdiv(EE * THD, tb), tb, 0, stream>>>(ei, sc, vbuf, agg);

  // BN_t + ReLU (no extra bias; bskip already in agg)
  k_bnrelu<GO><<<cdiv(NN * GO, tb), tb, 0, stream>>>(agg, nullptr, gt, bet, mt, vt);

  // ---- final linear: out = t @ Wfc + bfc
  sgemm<COUT, 4, 4><<<cdiv(NN, 128), 256, 0, stream>>>(agg, Wfc, bfc, (float*)d_out, NN, THD);
}

// Round 2
// 589.491 us; speedup vs baseline: 1.8464x; 1.8464x over previous
//
#include <hip/hip_runtime.h>
#include <math.h>

namespace {

constexpr int NN = 50000;
constexpr int EE = 400000;
constexpr int CIN = 512;
constexpr int GH = 128;
constexpr int GO = 64;
constexpr int THD = 64;
constexpr int HEADS = 4;
constexpr int COUT = 32;
constexpr float EPS = 1e-5f;

inline int cdiv(int a, int b) { return (a + b - 1) / b; }

// ---- init: zero deg (f32), cnt, cur (int) -------------------------------
__global__ void k_init0(float* deg, int* cnt, int* cur) {
  int i = blockIdx.x * blockDim.x + threadIdx.x;
  if (i < NN) { deg[i] = 0.0f; cnt[i] = 0; cur[i] = 0; }
}

// ---- per-edge: weighted degree + dst histogram --------------------------
__global__ void k_edge1(const int* __restrict__ ei, const float* __restrict__ w,
                        float* __restrict__ deg, int* __restrict__ cnt) {
  int e = blockIdx.x * blockDim.x + threadIdx.x;
  if (e < EE) {
    int d = ei[EE + e];
    atomicAdd(&deg[d], w[e]);
    atomicAdd(&cnt[d], 1);
  }
}

__global__ void k_dinv(float* deg) {
  int i = blockIdx.x * blockDim.x + threadIdx.x;
  if (i < NN) deg[i] = rsqrtf(deg[i] + 1.0f);  // + self-loop weight 1
}

// ---- exclusive scan of cnt[NN] -> ro[NN+1], single block ---------------
__launch_bounds__(1024) __global__ void k_scan(const int* __restrict__ cnt,
                                               int* __restrict__ ro) {
  __shared__ int wsum[16];
  __shared__ int carry_s;
  const int tid = threadIdx.x;
  const int lane = tid & 63;
  const int wv = tid >> 6;
  if (tid == 0) carry_s = 0;
  __syncthreads();
  for (int base = 0; base < NN; base += 1024) {
    int idx = base + tid;
    int v = idx < NN ? cnt[idx] : 0;
    int x = v;
#pragma unroll
    for (int s = 1; s < 64; s <<= 1) {
      int t = __shfl_up(x, s);
      if (lane >= s) x += t;
    }
    if (lane == 63) wsum[wv] = x;
    __syncthreads();
    if (wv == 0 && lane < 16) {
      int wsc = wsum[lane];
#pragma unroll
      for (int s = 1; s < 16; s <<= 1) {
        int t = __shfl_up(wsc, s);
        if (lane >= s) wsc += t;
      }
      wsum[lane] = wsc;  // inclusive scan of wave sums
    }
    __syncthreads();
    int waveoff = (wv == 0) ? 0 : wsum[wv - 1];
    int carry = carry_s;
    if (idx < NN) ro[idx] = carry + waveoff + x - v;  // exclusive
    __syncthreads();
    if (tid == 1023) carry_s = carry + wsum[15];
    __syncthreads();
  }
  if (threadIdx.x == 0) ro[NN] = carry_s;
}

// ---- fill CSR (src + norm), norm computed inline ------------------------
__global__ void k_fill(const int* __restrict__ ei, const float* __restrict__ w,
                       const float* __restrict__ dinv, const int* __restrict__ ro,
                       int* __restrict__ cur, int* __restrict__ csr_src,
                       float* __restrict__ csr_nrm) {
  int e = blockIdx.x * blockDim.x + threadIdx.x;
  if (e >= EE) return;
  int s = ei[e], d = ei[EE + e];
  int p = ro[d] + atomicAdd(&cur[d], 1);
  csr_src[p] = s;
  csr_nrm[p] = dinv[s] * w[e] * dinv[d];
}

// ---- generic fp32 SGEMM: C[M,F] = (ACC? C:0) + A[M,K] @ B[K,F] + bias ---
template <int F, int TM, int TN, bool ACC>
__launch_bounds__(256) __global__
void sgemm(const float* __restrict__ A, const float* __restrict__ B,
           const float* __restrict__ bias, float* __restrict__ C,
           int M, int K) {
  constexpr int KT = 32;
  constexpr int TC = F / TN;
  constexpr int TR = 256 / TC;
  constexpr int BM = TR * TM;
  constexpr int NJ = TN / 4;

  __shared__ float As[BM][KT + 4];
  __shared__ float Bs[KT][F];

  const int tid = threadIdx.x;
  const int tc = tid % TC;
  const int tr = tid / TC;
  const int m0 = blockIdx.x * BM;

  float acc[TM][TN];
#pragma unroll
  for (int i = 0; i < TM; ++i)
#pragma unroll
    for (int j = 0; j < TN; ++j) acc[i][j] = 0.0f;

  constexpr int totA4 = BM * KT / 4;
  constexpr int totB4 = KT * F / 4;

  for (int k0 = 0; k0 < K; k0 += KT) {
#pragma unroll
    for (int idx = tid; idx < totA4; idx += 256) {
      int flat = idx * 4;
      int r = flat / KT, c = flat % KT;
      float4 val = make_float4(0.f, 0.f, 0.f, 0.f);
      int gr = m0 + r;
      if (gr < M) val = *reinterpret_cast<const float4*>(A + (size_t)gr * K + k0 + c);
      *reinterpret_cast<float4*>(&As[r][c]) = val;
    }
    {
      const float4* Bg = reinterpret_cast<const float4*>(B + (size_t)k0 * F);
      float4* Bs4 = reinterpret_cast<float4*>(&Bs[0][0]);
#pragma unroll
      for (int idx = tid; idx < totB4; idx += 256) Bs4[idx] = Bg[idx];
    }
    __syncthreads();

#pragma unroll
    for (int kk = 0; kk < KT; ++kk) {
      float a[TM];
#pragma unroll
      for (int i = 0; i < TM; ++i) a[i] = As[tr * TM + i][kk];
      float4 b[NJ];
      const float4* Brow = reinterpret_cast<const float4*>(&Bs[kk][0]);
#pragma unroll
      for (int j = 0; j < NJ; ++j) b[j] = Brow[tc + j * TC];
#pragma unroll
      for (int i = 0; i < TM; ++i) {
#pragma unroll
        for (int j = 0; j < NJ; ++j) {
          acc[i][j * 4 + 0] += a[i] * b[j].x;
          acc[i][j * 4 + 1] += a[i] * b[j].y;
          acc[i][j * 4 + 2] += a[i] * b[j].z;
          acc[i][j * 4 + 3] += a[i] * b[j].w;
        }
      }
    }
    __syncthreads();
  }

  float4 bias4[NJ];
#pragma unroll
  for (int j = 0; j < NJ; ++j) {
    bias4[j] = bias ? reinterpret_cast<const float4*>(bias)[tc + j * TC]
                    : make_float4(0.f, 0.f, 0.f, 0.f);
  }
#pragma unroll
  for (int i = 0; i < TM; ++i) {
    int gr = m0 + tr * TM + i;
    if (gr >= M) continue;
    float4* Crow = reinterpret_cast<float4*>(C + (size_t)gr * F);
#pragma unroll
    for (int j = 0; j < NJ; ++j) {
      float4 v;
      v.x = acc[i][j * 4 + 0] + bias4[j].x;
      v.y = acc[i][j * 4 + 1] + bias4[j].y;
      v.z = acc[i][j * 4 + 2] + bias4[j].z;
      v.w = acc[i][j * 4 + 3] + bias4[j].w;
      if (ACC) {
        float4 old = Crow[tc + j * TC];
        v.x += old.x; v.y += old.y; v.z += old.z; v.w += old.w;
      }
      Crow[tc + j * TC] = v;
    }
  }
}

// ---- GCN propagate (CSR gather) + BN + ReLU, wave per dst ---------------
template <int F>
__launch_bounds__(256) __global__
void k_gcn(const int* __restrict__ ro, const int* __restrict__ csr_src,
           const float* __restrict__ csr_nrm, const float* __restrict__ h,
           const float* __restrict__ dinv, const float* __restrict__ bias,
           const float* __restrict__ g, const float* __restrict__ be,
           const float* __restrict__ m, const float* __restrict__ v,
           float* __restrict__ out) {
  const int wid = blockIdx.x * 4 + (threadIdx.x >> 6);
  const int lane = threadIdx.x & 63;
  if (wid >= NN) return;
  const float di = dinv[wid];
  const float di2 = di * di;
  const int p0 = ro[wid], p1 = ro[wid + 1];

  if (F == 128) {
    const float2* hr = reinterpret_cast<const float2*>(h + (size_t)wid * 128);
    float2 a = hr[lane];
    a.x *= di2; a.y *= di2;
    for (int p = p0; p < p1; ++p) {
      int s = csr_src[p];
      float w = csr_nrm[p];
      float2 hv = reinterpret_cast<const float2*>(h + (size_t)s * 128)[lane];
      a.x += w * hv.x; a.y += w * hv.y;
    }
    int f = 2 * lane;
    float2 gg = reinterpret_cast<const float2*>(g)[lane];
    float2 bb = reinterpret_cast<const float2*>(be)[lane];
    float2 mm = reinterpret_cast<const float2*>(m)[lane];
    float2 vv = reinterpret_cast<const float2*>(v)[lane];
    float2 bi = bias ? reinterpret_cast<const float2*>(bias)[lane]
                     : make_float2(0.f, 0.f);
    float s0 = gg.x * rsqrtf(vv.x + EPS);
    float s1 = gg.y * rsqrtf(vv.y + EPS);
    float y0 = (a.x + bi.x - mm.x) * s0 + bb.x;
    float y1 = (a.y + bi.y - mm.y) * s1 + bb.y;
    float2 o;
    o.x = y0 > 0.f ? y0 : 0.f;
    o.y = y1 > 0.f ? y1 : 0.f;
    reinterpret_cast<float2*>(out + (size_t)wid * 128)[lane] = o;
    (void)f;
  } else {
    float a = h[(size_t)wid * F + lane] * di2;
    for (int p = p0; p < p1; ++p) {
      int s = csr_src[p];
      float w = csr_nrm[p];
      a += w * h[(size_t)s * F + lane];
    }
    float sc = g[lane] * rsqrtf(v[lane] + EPS);
    float bi = bias ? bias[lane] : 0.f;
    float y = (a + bi - m[lane]) * sc + be[lane];
    out[(size_t)wid * F + lane] = y > 0.f ? y : 0.f;
  }
}

// ---- attention precompute: Mc[64][256], cvec[256] -----------------------
__global__ void k_prep_mc(const float* __restrict__ Wq, const float* __restrict__ Wk,
                          const float* __restrict__ bq, float* __restrict__ Mc,
                          float* __restrict__ cvec) {
  int i = blockIdx.x;        // input dim 0..63
  int col = threadIdx.x;     // h*64 + j
  int h = col >> 6, j = col & 63;
  float acc = 0.f;
  for (int t = 0; t < 64; ++t)
    acc += Wq[i * 256 + h * 64 + t] * Wk[j * 256 + h * 64 + t];
  Mc[i * 256 + col] = 0.125f * acc;
  if (i == 0) {
    float c = 0.f;
    for (int t = 0; t < 64; ++t) c += bq[h * 64 + t] * Wk[j * 256 + h * 64 + t];
    cvec[col] = 0.125f * c;
  }
}

// ---- Bv[256][64] = 0.25 * Wv permuted; bvs[64] = 0.25 * sum_h bv --------
__global__ void k_prep_bv(const float* __restrict__ Wv, const float* __restrict__ bv,
                          float* __restrict__ Bv, float* __restrict__ bvs) {
  int idx = blockIdx.x * blockDim.x + threadIdx.x;
  if (idx < 256 * 64) {
    int r = idx >> 6, t = idx & 63;
    int h = r >> 6, c = r & 63;
    Bv[idx] = 0.25f * Wv[c * 256 + h * 64 + t];
  }
  if (blockIdx.x == 0 && threadIdx.x < 64) {
    int t = threadIdx.x;
    float s = 0.f;
    for (int h = 0; h < HEADS; ++h) s += bv[h * 64 + t];
    bvs[t] = 0.25f * s;
  }
}

// ---- fused edge-softmax attention, wave per dst -------------------------
// u[d, h*64+c] = sum_e alpha_{e,h} * z[src_e, c]   (alpha normalized per head)
__launch_bounds__(256) __global__
void k_attn(const int* __restrict__ ro, const int* __restrict__ csr_src,
            const float* __restrict__ z, const float* __restrict__ qpp,
            float* __restrict__ u) {
  const int wid = blockIdx.x * 4 + (threadIdx.x >> 6);
  const int lane = threadIdx.x & 63;
  if (wid >= NN) return;

  float qh[4], mx[4], den[4], ua[4];
#pragma unroll
  for (int h = 0; h < 4; ++h) {
    qh[h] = qpp[(size_t)wid * 256 + h * 64 + lane];
    mx[h] = -1e30f;
    den[h] = 0.f;
    ua[h] = 0.f;
  }
  const int p0 = ro[wid], p1 = ro[wid + 1];
  for (int p = p0; p < p1; ++p) {
    int s = csr_src[p];
    float zl = z[(size_t)s * 64 + lane];
    float sc[4];
#pragma unroll
    for (int h = 0; h < 4; ++h) sc[h] = qh[h] * zl;
#pragma unroll
    for (int off = 32; off; off >>= 1) {
#pragma unroll
      for (int h = 0; h < 4; ++h) sc[h] += __shfl_xor(sc[h], off);
    }
#pragma unroll
    for (int h = 0; h < 4; ++h) {
      float nm = fmaxf(mx[h], sc[h]);
      float scale = __expf(mx[h] - nm);
      float pe = __expf(sc[h] - nm);
      den[h] = den[h] * scale + pe;
      ua[h] = ua[h] * scale + pe * zl;
      mx[h] = nm;
    }
  }
#pragma unroll
  for (int h = 0; h < 4; ++h)
    u[(size_t)wid * 256 + h * 64 + lane] = ua[h] / (den[h] + 1e-16f);
}

// ---- BN + ReLU (post-attention) -----------------------------------------
template <int F>
__global__ void k_bnrelu(float* __restrict__ h, const float* __restrict__ g,
                         const float* __restrict__ be, const float* __restrict__ m,
                         const float* __restrict__ v) {
  int i = blockIdx.x * blockDim.x + threadIdx.x;
  if (i < NN * F) {
    int f = i % F;
    float s = g[f] * rsqrtf(v[f] + EPS);
    float y = (h[i] - m[f]) * s + be[f];
    h[i] = y > 0.0f ? y : 0.0f;
  }
}

}  // namespace

extern "C" void kernel_launch(void* const* d_in, const int* in_sizes, int n_in,
                              void* d_out, int out_size, void* d_ws, size_t ws_size,
                              hipStream_t stream) {
  const float* x   = (const float*)d_in[0];
  const int*   ei  = (const int*)d_in[1];
  const float* ew  = (const float*)d_in[2];
  const float* W1  = (const float*)d_in[3];
  const float* b1  = (const float*)d_in[4];
  const float* g1  = (const float*)d_in[5];
  const float* be1 = (const float*)d_in[6];
  const float* m1  = (const float*)d_in[7];
  const float* v1  = (const float*)d_in[8];
  const float* W2  = (const float*)d_in[9];
  const float* b2  = (const float*)d_in[10];
  const float* g2  = (const float*)d_in[11];
  const float* be2 = (const float*)d_in[12];
  const float* m2  = (const float*)d_in[13];
  const float* v2  = (const float*)d_in[14];
  const float* Wq  = (const float*)d_in[15];
  const float* bq  = (const float*)d_in[16];
  const float* Wk  = (const float*)d_in[17];
  // bk unused: its dst-side contribution is softmax-shift-invariant (dropped),
  // src-side enters via cvec using bq/Wk; with bk the symmetric term is cvec' —
  // handled below. (bk enters score as z_d·(Wq_h bk_h): dst-only => dropped.)
  const float* Wv  = (const float*)d_in[19];
  const float* bv  = (const float*)d_in[20];
  const float* Wsk = (const float*)d_in[21];
  const float* bsk = (const float*)d_in[22];
  const float* gt  = (const float*)d_in[23];
  const float* bet = (const float*)d_in[24];
  const float* mt  = (const float*)d_in[25];
  const float* vt  = (const float*)d_in[26];
  const float* Wfc = (const float*)d_in[27];
  const float* bfc = (const float*)d_in[28];

  float* ws = (float*)d_ws;
  float* dinv    = ws;                          // N
  int*   cnt     = (int*)(dinv + NN);           // N
  int*   cur     = cnt + NN;                    // N
  int*   ro      = cur + NN;                    // N+1
  int*   csr_src = ro + NN + 1;                 // E
  float* csr_nrm = (float*)(csr_src + EE);      // E
  float* h1      = csr_nrm + EE;                // N*128
  float* a1      = h1 + (size_t)NN * GH;        // N*128
  float* h2      = a1 + (size_t)NN * GH;        // N*64
  float* z       = h2 + (size_t)NN * GO;        // N*64
  float* qpp     = z + (size_t)NN * GO;         // N*256
  float* u       = qpp + (size_t)NN * 256;      // N*256
  float* agg     = u + (size_t)NN * 256;        // N*64
  float* Mc      = agg + (size_t)NN * GO;       // 64*256
  float* cvec    = Mc + 64 * 256;               // 256
  float* Bv      = cvec + 256;                  // 256*64
  float* bvs     = Bv + 256 * 64;               // 64

  const int tb = 256;

  // graph prep + CSR
  k_init0<<<cdiv(NN, tb), tb, 0, stream>>>(dinv, cnt, cur);
  k_edge1<<<cdiv(EE, tb), tb, 0, stream>>>(ei, ew, dinv, cnt);
  k_dinv<<<cdiv(NN, tb), tb, 0, stream>>>(dinv);
  k_scan<<<1, 1024, 0, stream>>>(cnt, ro);
  k_fill<<<cdiv(EE, tb), tb, 0, stream>>>(ei, ew, dinv, ro, cur, csr_src, csr_nrm);

  // attention weight precompute (independent of activations)
  k_prep_mc<<<64, 256, 0, stream>>>(Wq, Wk, bq, Mc, cvec);
  k_prep_bv<<<64, 256, 0, stream>>>(Wv, bv, Bv, bvs);

  // GCN layer 1
  sgemm<GH, 8, 8, false><<<cdiv(NN, 128), 256, 0, stream>>>(x, W1, nullptr, h1, NN, CIN);
  k_gcn<GH><<<cdiv(NN, 4), 256, 0, stream>>>(ro, csr_src, csr_nrm, h1, dinv,
                                             b1, g1, be1, m1, v1, a1);
  // GCN layer 2
  sgemm<GO, 4, 8, false><<<cdiv(NN, 128), 256, 0, stream>>>(a1, W2, nullptr, h2, NN, GH);
  k_gcn<GO><<<cdiv(NN, 4), 256, 0, stream>>>(ro, csr_src, csr_nrm, h2, dinv,
                                             b2, g2, be2, m2, v2, z);

  // TransformerConv: Q'' = z @ Mc + cvec  (N x 256)
  sgemm<256, 8, 8, false><<<cdiv(NN, 64), 256, 0, stream>>>(z, Mc, cvec, qpp, NN, GO);
  k_attn<<<cdiv(NN, 4), 256, 0, stream>>>(ro, csr_src, z, qpp, u);

  // agg = z @ Wskip + bskip ; agg += u @ Bv + bvs
  sgemm<GO, 4, 8, false><<<cdiv(NN, 128), 256, 0, stream>>>(z, Wsk, bsk, agg, NN, GO);
  sgemm<GO, 4, 8, true><<<cdiv(NN, 128), 256, 0, stream>>>(u, Bv, bvs, agg, NN, 256);

  // BN_t + ReLU, then final linear
  k_bnrelu<GO><<<cdiv(NN * GO, tb), tb, 0, stream>>>(agg, gt, bet, mt, vt);
  sgemm<COUT, 4, 4, false><<<cdiv(NN, 128), 256, 0, stream>>>(agg, Wfc, bfc,
                                                              (float*)d_out, NN, THD);
}

// Round 3
// 477.277 us; speedup vs baseline: 2.2805x; 1.2351x over previous
//
#include <hip/hip_runtime.h>
#include <math.h>

namespace {

constexpr int NN = 50000;
constexpr int EE = 400000;
constexpr int CIN = 512;
constexpr int GH = 128;
constexpr int GO = 64;
constexpr int HEADS = 4;
constexpr int COUT = 32;
constexpr float EPS = 1e-5f;

typedef __attribute__((ext_vector_type(8))) short short8;
typedef __attribute__((ext_vector_type(4))) float f32x4;
typedef __attribute__((ext_vector_type(4))) unsigned int uint4v;

inline int cdiv(int a, int b) { return (a + b - 1) / b; }

__device__ __forceinline__ void split2(float x, unsigned short& hi, unsigned short& lo) {
  unsigned b = __float_as_uint(x);
  hi = (unsigned short)(b >> 16);
  float hf = __uint_as_float(b & 0xFFFF0000u);
  lo = (unsigned short)(__float_as_uint(x - hf) >> 16);
}

// ---- init ---------------------------------------------------------------
__global__ void k_init0(float* deg, int* cnt, int* cur) {
  int i = blockIdx.x * blockDim.x + threadIdx.x;
  if (i < NN) { deg[i] = 0.0f; cnt[i] = 0; cur[i] = 0; }
}

__global__ void k_edge1(const int* __restrict__ ei, const float* __restrict__ w,
                        float* __restrict__ deg, int* __restrict__ cnt) {
  int e = blockIdx.x * blockDim.x + threadIdx.x;
  if (e < EE) {
    int d = ei[EE + e];
    atomicAdd(&deg[d], w[e]);
    atomicAdd(&cnt[d], 1);
  }
}

__global__ void k_dinv(float* deg) {
  int i = blockIdx.x * blockDim.x + threadIdx.x;
  if (i < NN) deg[i] = rsqrtf(deg[i] + 1.0f);
}

// ---- exclusive scan of cnt[NN] -> ro, single block ----------------------
__launch_bounds__(1024) __global__ void k_scan(const int* __restrict__ cnt,
                                               int* __restrict__ ro) {
  __shared__ int wsum[16];
  __shared__ int carry_s;
  const int tid = threadIdx.x;
  const int lane = tid & 63;
  const int wv = tid >> 6;
  if (tid == 0) carry_s = 0;
  __syncthreads();
  for (int base = 0; base < NN; base += 1024) {
    int idx = base + tid;
    int v = idx < NN ? cnt[idx] : 0;
    int x = v;
#pragma unroll
    for (int s = 1; s < 64; s <<= 1) {
      int t = __shfl_up(x, s);
      if (lane >= s) x += t;
    }
    if (lane == 63) wsum[wv] = x;
    __syncthreads();
    if (wv == 0 && lane < 16) {
      int wsc = wsum[lane];
#pragma unroll
      for (int s = 1; s < 16; s <<= 1) {
        int t = __shfl_up(wsc, s);
        if (lane >= s) wsc += t;
      }
      wsum[lane] = wsc;
    }
    __syncthreads();
    int waveoff = (wv == 0) ? 0 : wsum[wv - 1];
    int carry = carry_s;
    if (idx < NN) ro[idx] = carry + waveoff + x - v;
    __syncthreads();
    if (tid == 1023) carry_s = carry + wsum[15];
    __syncthreads();
  }
  if (threadIdx.x == 0) ro[NN] = carry_s;
}

__global__ void k_fill(const int* __restrict__ ei, const float* __restrict__ w,
                       const float* __restrict__ dinv, const int* __restrict__ ro,
                       int* __restrict__ cur, int* __restrict__ csr_src,
                       float* __restrict__ csr_nrm) {
  int e = blockIdx.x * blockDim.x + threadIdx.x;
  if (e >= EE) return;
  int s = ei[e], d = ei[EE + e];
  int p = ro[d] + atomicAdd(&cur[d], 1);
  csr_src[p] = s;
  csr_nrm[p] = dinv[s] * w[e] * dinv[d];
}

// ---- B-matrix hi/lo split + transpose: B[K][F] f32 -> {hi[F][K], lo[F][K]} bf16
__global__ void k_split(const float* __restrict__ B, unsigned short* __restrict__ Bp,
                        int K, int F) {
  int idx = blockIdx.x * blockDim.x + threadIdx.x;
  if (idx >= K * F) return;
  int k = idx / F, f = idx - k * F;
  unsigned short hi, lo;
  split2(B[idx], hi, lo);
  Bp[f * K + k] = hi;
  Bp[(size_t)F * K + f * K + k] = lo;
}

// ---- MFMA GEMM: C[M,F] = A[M,K] @ B (+bias) (+ACC) (+BN/ReLU) -----------
// A fp32 (converted to bf16 hi/lo on the fly); Bp pre-split [2][F][K] bf16.
// BM=64 rows/block, 256 threads = 4 waves in 2x2; BN columns per block.
template <int BN, bool ACC, bool BNR>
__launch_bounds__(256, 2) __global__
void mgemm(const float* __restrict__ A, const unsigned short* __restrict__ Bp,
           const float* __restrict__ bias, float* __restrict__ C,
           int M, int K, int F,
           const float* __restrict__ bn_g, const float* __restrict__ bn_b,
           const float* __restrict__ bn_m, const float* __restrict__ bn_v) {
  constexpr int BM = 64;
  constexpr int BK = 64;
  constexpr int NR = BN / 32;  // 16-col frags per wave

  __shared__ unsigned short lds[(BM + BN) * BK * 2];
  unsigned short* Ah = lds;                 // [64][64]
  unsigned short* Al = Ah + BM * BK;
  unsigned short* Bh = Al + BM * BK;        // [BN][64]
  unsigned short* Bl = Bh + BN * BK;

  const int tid = threadIdx.x;
  const int lane = tid & 63;
  const int wid = tid >> 6;
  const int wr = wid >> 1, wc = wid & 1;
  const int l15 = lane & 15, lhi = lane >> 4;
  const int m0 = blockIdx.x * BM;
  const int n0 = blockIdx.y * BN;

  f32x4 acc[2][NR];
#pragma unroll
  for (int mi = 0; mi < 2; ++mi)
#pragma unroll
    for (int ni = 0; ni < NR; ++ni) acc[mi][ni] = (f32x4)0.0f;

  for (int k0 = 0; k0 < K; k0 += BK) {
    // ---- stage A tile: thread t -> row t>>2, 16-float chunk t&3
    {
      const int r = tid >> 2, ch = tid & 3;
      const int gr = m0 + r;
      float xv[16];
      if (gr < M) {
        const float4* src =
            reinterpret_cast<const float4*>(A + (size_t)gr * K + k0 + ch * 16);
#pragma unroll
        for (int i = 0; i < 4; ++i) {
          float4 f = src[i];
          xv[i * 4 + 0] = f.x; xv[i * 4 + 1] = f.y;
          xv[i * 4 + 2] = f.z; xv[i * 4 + 3] = f.w;
        }
      } else {
#pragma unroll
        for (int i = 0; i < 16; ++i) xv[i] = 0.0f;
      }
      short8 vh0, vl0, vh1, vl1;
#pragma unroll
      for (int i = 0; i < 8; ++i) {
        unsigned short h, l;
        split2(xv[i], h, l);
        vh0[i] = (short)h; vl0[i] = (short)l;
      }
#pragma unroll
      for (int i = 0; i < 8; ++i) {
        unsigned short h, l;
        split2(xv[8 + i], h, l);
        vh1[i] = (short)h; vl1[i] = (short)l;
      }
      const int base = r * 128 + ch * 32;        // bytes within tile
      const int sw = (r & 7) << 4;
      *reinterpret_cast<short8*>((char*)Ah + (base ^ sw)) = vh0;
      *reinterpret_cast<short8*>((char*)Ah + ((base + 16) ^ sw)) = vh1;
      *reinterpret_cast<short8*>((char*)Al + (base ^ sw)) = vl0;
      *reinterpret_cast<short8*>((char*)Al + ((base + 16) ^ sw)) = vl1;
    }
    // ---- stage B tile: BN*16 chunks of 8 bf16 across hi+lo planes
    {
#pragma unroll
      for (int it = 0; it < BN / 16; ++it) {
        int id = tid + it * 256;          // 0 .. 2*BN*8-1
        int kc = id & 7;
        int colp = id >> 3;               // plane*BN + col
        int col = colp & (BN - 1);
        int plane = colp >> (BN == 32 ? 5 : (BN == 64 ? 6 : 7));
        const uint4v gv = *reinterpret_cast<const uint4v*>(
            Bp + ((size_t)plane * F + n0 + col) * K + k0 + kc * 8);
        unsigned short* dst = plane ? Bl : Bh;
        const int base = col * 128 + kc * 16;
        *reinterpret_cast<uint4v*>((char*)dst + (base ^ ((col & 7) << 4))) = gv;
      }
    }
    __syncthreads();

#pragma unroll
    for (int ks = 0; ks < 2; ++ks) {
      short8 ahf[2], alf[2], bhf[NR], blf[NR];
#pragma unroll
      for (int mi = 0; mi < 2; ++mi) {
        int row = wr * 32 + mi * 16 + l15;
        int off = (row * 128 + (ks * 32 + lhi * 8) * 2) ^ ((row & 7) << 4);
        ahf[mi] = *reinterpret_cast<const short8*>((const char*)Ah + off);
        alf[mi] = *reinterpret_cast<const short8*>((const char*)Al + off);
      }
#pragma unroll
      for (int ni = 0; ni < NR; ++ni) {
        int col = wc * (BN / 2) + ni * 16 + l15;
        int off = (col * 128 + (ks * 32 + lhi * 8) * 2) ^ ((col & 7) << 4);
        bhf[ni] = *reinterpret_cast<const short8*>((const char*)Bh + off);
        blf[ni] = *reinterpret_cast<const short8*>((const char*)Bl + off);
      }
#pragma unroll
      for (int mi = 0; mi < 2; ++mi)
#pragma unroll
        for (int ni = 0; ni < NR; ++ni) {
          acc[mi][ni] = __builtin_amdgcn_mfma_f32_16x16x32_bf16(
              ahf[mi], bhf[ni], acc[mi][ni], 0, 0, 0);
          acc[mi][ni] = __builtin_amdgcn_mfma_f32_16x16x32_bf16(
              ahf[mi], blf[ni], acc[mi][ni], 0, 0, 0);
          acc[mi][ni] = __builtin_amdgcn_mfma_f32_16x16x32_bf16(
              alf[mi], bhf[ni], acc[mi][ni], 0, 0, 0);
        }
    }
    __syncthreads();
  }

  // ---- epilogue: C/D layout col=lane&15, row=(lane>>4)*4+reg
#pragma unroll
  for (int mi = 0; mi < 2; ++mi) {
#pragma unroll
    for (int ni = 0; ni < NR; ++ni) {
      const int col = n0 + wc * (BN / 2) + ni * 16 + l15;
      const float bv = bias ? bias[col] : 0.0f;
      float bns = 0.f, bnb = 0.f, bnm = 0.f;
      if (BNR) {
        bns = bn_g[col] * rsqrtf(bn_v[col] + EPS);
        bnb = bn_b[col];
        bnm = bn_m[col];
      }
#pragma unroll
      for (int r4 = 0; r4 < 4; ++r4) {
        const int row = m0 + wr * 32 + mi * 16 + lhi * 4 + r4;
        if (row < M) {
          float vout = acc[mi][ni][r4] + bv;
          if (ACC) vout += C[(size_t)row * F + col];
          if (BNR) {
            vout = (vout - bnm) * bns + bnb;
            vout = vout > 0.f ? vout : 0.f;
          }
          C[(size_t)row * F + col] = vout;
        }
      }
    }
  }
}

// ---- GCN propagate (CSR gather) + BN + ReLU, wave per dst ---------------
template <int F>
__launch_bounds__(256) __global__
void k_gcn(const int* __restrict__ ro, const int* __restrict__ csr_src,
           const float* __restrict__ csr_nrm, const float* __restrict__ h,
           const float* __restrict__ dinv, const float* __restrict__ bias,
           const float* __restrict__ g, const float* __restrict__ be,
           const float* __restrict__ m, const float* __restrict__ v,
           float* __restrict__ out) {
  const int wid = blockIdx.x * 4 + (threadIdx.x >> 6);
  const int lane = threadIdx.x & 63;
  if (wid >= NN) return;
  const float di = dinv[wid];
  const float di2 = di * di;
  const int p0 = ro[wid], p1 = ro[wid + 1];

  if (F == 128) {
    const float2* hr = reinterpret_cast<const float2*>(h + (size_t)wid * 128);
    float2 a = hr[lane];
    a.x *= di2; a.y *= di2;
    for (int p = p0; p < p1; ++p) {
      int s = csr_src[p];
      float w = csr_nrm[p];
      float2 hv = reinterpret_cast<const float2*>(h + (size_t)s * 128)[lane];
      a.x += w * hv.x; a.y += w * hv.y;
    }
    float2 gg = reinterpret_cast<const float2*>(g)[lane];
    float2 bb = reinterpret_cast<const float2*>(be)[lane];
    float2 mm = reinterpret_cast<const float2*>(m)[lane];
    float2 vv = reinterpret_cast<const float2*>(v)[lane];
    float2 bi = bias ? reinterpret_cast<const float2*>(bias)[lane]
                     : make_float2(0.f, 0.f);
    float s0 = gg.x * rsqrtf(vv.x + EPS);
    float s1 = gg.y * rsqrtf(vv.y + EPS);
    float y0 = (a.x + bi.x - mm.x) * s0 + bb.x;
    float y1 = (a.y + bi.y - mm.y) * s1 + bb.y;
    float2 o;
    o.x = y0 > 0.f ? y0 : 0.f;
    o.y = y1 > 0.f ? y1 : 0.f;
    reinterpret_cast<float2*>(out + (size_t)wid * 128)[lane] = o;
  } else {
    float a = h[(size_t)wid * F + lane] * di2;
    for (int p = p0; p < p1; ++p) {
      int s = csr_src[p];
      float w = csr_nrm[p];
      a += w * h[(size_t)s * F + lane];
    }
    float sc = g[lane] * rsqrtf(v[lane] + EPS);
    float bi = bias ? bias[lane] : 0.f;
    float y = (a + bi - m[lane]) * sc + be[lane];
    out[(size_t)wid * F + lane] = y > 0.f ? y : 0.f;
  }
}

// ---- attention precompute: Mc[64][256], cvec[256] -----------------------
__global__ void k_prep_mc(const float* __restrict__ Wq, const float* __restrict__ Wk,
                          const float* __restrict__ bq, float* __restrict__ Mc,
                          float* __restrict__ cvec) {
  int i = blockIdx.x;
  int col = threadIdx.x;
  int h = col >> 6, j = col & 63;
  float acc = 0.f;
  for (int t = 0; t < 64; ++t)
    acc += Wq[i * 256 + h * 64 + t] * Wk[j * 256 + h * 64 + t];
  Mc[i * 256 + col] = 0.125f * acc;
  if (i == 0) {
    float c = 0.f;
    for (int t = 0; t < 64; ++t) c += bq[h * 64 + t] * Wk[j * 256 + h * 64 + t];
    cvec[col] = 0.125f * c;
  }
}

// ---- Bv[256][64] = 0.25 * Wv permuted; bvs[64] = 0.25 * sum_h bv --------
__global__ void k_prep_bv(const float* __restrict__ Wv, const float* __restrict__ bv,
                          float* __restrict__ Bv, float* __restrict__ bvs) {
  int idx = blockIdx.x * blockDim.x + threadIdx.x;
  if (idx < 256 * 64) {
    int r = idx >> 6, t = idx & 63;
    int h = r >> 6, c = r & 63;
    Bv[idx] = 0.25f * Wv[c * 256 + h * 64 + t];
  }
  if (blockIdx.x == 0 && threadIdx.x < 64) {
    int t = threadIdx.x;
    float s = 0.f;
    for (int h = 0; h < HEADS; ++h) s += bv[h * 64 + t];
    bvs[t] = 0.25f * s;
  }
}

// ---- fused edge-softmax attention, wave per dst -------------------------
__launch_bounds__(256) __global__
void k_attn(const int* __restrict__ ro, const int* __restrict__ csr_src,
            const float* __restrict__ z, const float* __restrict__ qpp,
            float* __restrict__ u) {
  const int wid = blockIdx.x * 4 + (threadIdx.x >> 6);
  const int lane = threadIdx.x & 63;
  if (wid >= NN) return;

  float qh[4], mx[4], den[4], ua[4];
#pragma unroll
  for (int h = 0; h < 4; ++h) {
    qh[h] = qpp[(size_t)wid * 256 + h * 64 + lane];
    mx[h] = -1e30f;
    den[h] = 0.f;
    ua[h] = 0.f;
  }
  const int p0 = ro[wid], p1 = ro[wid + 1];
  for (int p = p0; p < p1; ++p) {
    int s = csr_src[p];
    float zl = z[(size_t)s * 64 + lane];
    float sc[4];
#pragma unroll
    for (int h = 0; h < 4; ++h) sc[h] = qh[h] * zl;
#pragma unroll
    for (int off = 32; off; off >>= 1) {
#pragma unroll
      for (int h = 0; h < 4; ++h) sc[h] += __shfl_xor(sc[h], off);
    }
#pragma unroll
    for (int h = 0; h < 4; ++h) {
      float nm = fmaxf(mx[h], sc[h]);
      float scale = __expf(mx[h] - nm);
      float pe = __expf(sc[h] - nm);
      den[h] = den[h] * scale + pe;
      ua[h] = ua[h] * scale + pe * zl;
      mx[h] = nm;
    }
  }
#pragma unroll
  for (int h = 0; h < 4; ++h)
    u[(size_t)wid * 256 + h * 64 + lane] = ua[h] / (den[h] + 1e-16f);
}

}  // namespace

extern "C" void kernel_launch(void* const* d_in, const int* in_sizes, int n_in,
                              void* d_out, int out_size, void* d_ws, size_t ws_size,
                              hipStream_t stream) {
  const float* x   = (const float*)d_in[0];
  const int*   ei  = (const int*)d_in[1];
  const float* ew  = (const float*)d_in[2];
  const float* W1  = (const float*)d_in[3];
  const float* b1  = (const float*)d_in[4];
  const float* g1  = (const float*)d_in[5];
  const float* be1 = (const float*)d_in[6];
  const float* m1  = (const float*)d_in[7];
  const float* v1  = (const float*)d_in[8];
  const float* W2  = (const float*)d_in[9];
  const float* b2  = (const float*)d_in[10];
  const float* g2  = (const float*)d_in[11];
  const float* be2 = (const float*)d_in[12];
  const float* m2  = (const float*)d_in[13];
  const float* v2  = (const float*)d_in[14];
  const float* Wq  = (const float*)d_in[15];
  const float* bq  = (const float*)d_in[16];
  const float* Wk  = (const float*)d_in[17];
  const float* Wv  = (const float*)d_in[19];
  const float* bv  = (const float*)d_in[20];
  const float* Wsk = (const float*)d_in[21];
  const float* bsk = (const float*)d_in[22];
  const float* gt  = (const float*)d_in[23];
  const float* bet = (const float*)d_in[24];
  const float* mt  = (const float*)d_in[25];
  const float* vt  = (const float*)d_in[26];
  const float* Wfc = (const float*)d_in[27];
  const float* bfc = (const float*)d_in[28];

  float* ws = (float*)d_ws;
  float* dinv    = ws;                          // N
  int*   cnt     = (int*)(dinv + NN);           // N
  int*   cur     = cnt + NN;                    // N
  int*   ro      = cur + NN;                    // N+1 (padded to 50016)
  int*   csr_src = ro + 50016;                  // E
  float* csr_nrm = (float*)(csr_src + EE);      // E
  float* h1      = csr_nrm + EE;                // N*128
  float* a1      = h1 + (size_t)NN * GH;        // N*128
  float* h2      = a1 + (size_t)NN * GH;        // N*64
  float* z       = h2 + (size_t)NN * GO;        // N*64
  float* qpp     = z + (size_t)NN * GO;         // N*256
  float* u       = qpp + (size_t)NN * 256;      // N*256
  float* agg     = u + (size_t)NN * 256;        // N*64
  float* Mc      = agg + (size_t)NN * GO;       // 64*256
  float* cvec    = Mc + 64 * 256;               // 256
  float* Bvm     = cvec + 256;                  // 256*64
  float* bvs     = Bvm + 256 * 64;              // 64
  unsigned short* W1p  = (unsigned short*)(bvs + 64);  // 2*512*128
  unsigned short* W2p  = W1p + 2 * 512 * 128;          // 2*128*64
  unsigned short* Mcp  = W2p + 2 * 128 * 64;           // 2*64*256
  unsigned short* Wskp = Mcp + 2 * 64 * 256;           // 2*64*64
  unsigned short* Bvp  = Wskp + 2 * 64 * 64;           // 2*256*64
  unsigned short* Wfcp = Bvp + 2 * 256 * 64;           // 2*64*32

  const int tb = 256;
  const int gM = cdiv(NN, 64);  // 782 row-blocks

  // graph prep + CSR
  k_init0<<<cdiv(NN, tb), tb, 0, stream>>>(dinv, cnt, cur);
  k_edge1<<<cdiv(EE, tb), tb, 0, stream>>>(ei, ew, dinv, cnt);
  k_dinv<<<cdiv(NN, tb), tb, 0, stream>>>(dinv);
  k_scan<<<1, 1024, 0, stream>>>(cnt, ro);
  k_fill<<<cdiv(EE, tb), tb, 0, stream>>>(ei, ew, dinv, ro, cur, csr_src, csr_nrm);

  // attention weight precompute + B splits
  k_prep_mc<<<64, 256, 0, stream>>>(Wq, Wk, bq, Mc, cvec);
  k_prep_bv<<<64, 256, 0, stream>>>(Wv, bv, Bvm, bvs);
  k_split<<<cdiv(512 * 128, tb), tb, 0, stream>>>(W1, W1p, 512, 128);
  k_split<<<cdiv(128 * 64, tb), tb, 0, stream>>>(W2, W2p, 128, 64);
  k_split<<<cdiv(64 * 256, tb), tb, 0, stream>>>(Mc, Mcp, 64, 256);
  k_split<<<cdiv(64 * 64, tb), tb, 0, stream>>>(Wsk, Wskp, 64, 64);
  k_split<<<cdiv(256 * 64, tb), tb, 0, stream>>>(Bvm, Bvp, 256, 64);
  k_split<<<cdiv(64 * 32, tb), tb, 0, stream>>>(Wfc, Wfcp, 64, 32);

  // GCN layer 1: h1 = x @ W1 ; propagate+BN+ReLU
  mgemm<128, false, false><<<dim3(gM, 1), 256, 0, stream>>>(
      x, W1p, nullptr, h1, NN, CIN, GH, nullptr, nullptr, nullptr, nullptr);
  k_gcn<GH><<<cdiv(NN, 4), 256, 0, stream>>>(ro, csr_src, csr_nrm, h1, dinv,
                                             b1, g1, be1, m1, v1, a1);
  // GCN layer 2
  mgemm<64, false, false><<<dim3(gM, 1), 256, 0, stream>>>(
      a1, W2p, nullptr, h2, NN, GH, GO, nullptr, nullptr, nullptr, nullptr);
  k_gcn<GO><<<cdiv(NN, 4), 256, 0, stream>>>(ro, csr_src, csr_nrm, h2, dinv,
                                             b2, g2, be2, m2, v2, z);

  // TransformerConv: Q'' = z @ Mc + cvec
  mgemm<128, false, false><<<dim3(gM, 2), 256, 0, stream>>>(
      z, Mcp, cvec, qpp, NN, GO, 256, nullptr, nullptr, nullptr, nullptr);
  k_attn<<<cdiv(NN, 4), 256, 0, stream>>>(ro, csr_src, z, qpp, u);

  // agg = z @ Wskip + bskip ; agg += u @ Bv + bvs ; BN_t + ReLU fused
  mgemm<64, false, false><<<dim3(gM, 1), 256, 0, stream>>>(
      z, Wskp, bsk, agg, NN, GO, GO, nullptr, nullptr, nullptr, nullptr);
  mgemm<64, true, true><<<dim3(gM, 1), 256, 0, stream>>>(
      u, Bvp, bvs, agg, NN, 256, GO, gt, bet, mt, vt);

  // final linear
  mgemm<32, false, false><<<dim3(gM, 1), 256, 0, stream>>>(
      agg, Wfcp, bfc, (float*)d_out, NN, GO, COUT, nullptr, nullptr, nullptr, nullptr);
}